// Round 2
// baseline (9060.813 us; speedup 1.0000x reference)
//
#include <hip/hip_runtime.h>
#include <cstdint>

typedef _Float16 f16;
typedef f16      f16x8 __attribute__((ext_vector_type(8)));
typedef float    f32x4 __attribute__((ext_vector_type(4)));
typedef uint32_t u32;
typedef u32      u32x4 __attribute__((ext_vector_type(4)));

#define NB   32
#define TT   1024
#define DD   512
#define HH   512
#define NWG  64
#define NBHH (NB*HH)   // dwords per tagged h buffer

__device__ __forceinline__ float fsig(float x) {
    return __builtin_amdgcn_rcpf(1.0f + __expf(-x));
}
__device__ __forceinline__ float ftanh(float x) {
    return 1.0f - 2.0f * __builtin_amdgcn_rcpf(__expf(2.0f * x) + 1.0f);
}
__device__ __forceinline__ u32 pkmin(u32 a, u32 b) {
    u32 d; asm("v_pk_min_u16 %0, %1, %2" : "=v"(d) : "v"(a), "v"(b)); return d;
}

// ---- setup kernels -------------------------------------------------------

__global__ void k_cast_x(const float* __restrict__ x, f16* __restrict__ x16) {
    int i = (blockIdx.x * 256 + threadIdx.x) * 8;
    float4 a = *(const float4*)(x + i);
    float4 c = *(const float4*)(x + i + 4);
    f16x8 v;
    v[0] = (f16)a.x; v[1] = (f16)a.y; v[2] = (f16)a.z; v[3] = (f16)a.w;
    v[4] = (f16)c.x; v[5] = (f16)c.y; v[6] = (f16)c.z; v[7] = (f16)c.w;
    *(f16x8*)(x16 + i) = v;
}

// W (512 x 2048 row-major) -> Wp[colp][k] f16; colp = wg*32 + j*4 + gate,
// col2048 = gate*512 + wg*8 + j.
__global__ void k_perm_w(const float* __restrict__ W, f16* __restrict__ Wp) {
    int tid = blockIdx.x * 256 + threadIdx.x;   // 2048*512
    int colp = tid >> 9, k = tid & 511;
    int wg = colp >> 5, c = colp & 31;
    int gate = c & 3, j = c >> 2;
    int col = gate * 512 + wg * 8 + j;
    Wp[tid] = (f16)W[k * 2048 + col];
}

// h0 -> tagged dwords (tag 0) in buffer 0, written through to IF.
__global__ void k_h0(const float* __restrict__ h0, u32* __restrict__ hb32) {
    int i = blockIdx.x * 256 + threadIdx.x;     // 32*512
    f16 v = (f16)h0[i];
    u32 pub = (u32)*(unsigned short*)&v;        // tag 0 in high 16
    u32* p = hb32 + i;
    asm volatile("global_store_dword %0, %1, off sc0 sc1" :: "v"(p), "v"(pub) : "memory");
}

// ---- tagged-load helpers -------------------------------------------------

#define HL(I, OFFSTR) asm volatile("global_load_dwordx4 %0, %1, off" OFFSTR " sc0 sc1" \
                                   : "=v"(raw[I]) : "v"(hb))
__device__ __forceinline__ void issue_h(u32x4* raw, const u32* hb) {
    HL(0,  "");            HL(1,  " offset:16");
    HL(2,  " offset:128"); HL(3,  " offset:144");
    HL(4,  " offset:256"); HL(5,  " offset:272");
    HL(6,  " offset:384"); HL(7,  " offset:400");
    HL(8,  " offset:512"); HL(9,  " offset:528");
    HL(10, " offset:640"); HL(11, " offset:656");
    HL(12, " offset:768"); HL(13, " offset:784");
    HL(14, " offset:896"); HL(15, " offset:912");
    HL(16, " offset:1024"); HL(17, " offset:1040");
    HL(18, " offset:1152"); HL(19, " offset:1168");
    HL(20, " offset:1280"); HL(21, " offset:1296");
    HL(22, " offset:1408"); HL(23, " offset:1424");
    HL(24, " offset:1536"); HL(25, " offset:1552");
    HL(26, " offset:1664"); HL(27, " offset:1680");
    HL(28, " offset:1792"); HL(29, " offset:1808");
    HL(30, " offset:1920"); HL(31, " offset:1936");
}

#define XL(I, OFFSTR) asm volatile("global_load_dwordx4 %0, %1, off" OFFSTR \
                                   : "=v"(ax[I]) : "v"(xp))
__device__ __forceinline__ void issue_x(f16x8* ax, const f16* xp) {
    XL(0,  "");            XL(1,  " offset:64");
    XL(2,  " offset:128"); XL(3,  " offset:192");
    XL(4,  " offset:256"); XL(5,  " offset:320");
    XL(6,  " offset:384"); XL(7,  " offset:448");
    XL(8,  " offset:512"); XL(9,  " offset:576");
    XL(10, " offset:640"); XL(11, " offset:704");
    XL(12, " offset:768"); XL(13, " offset:832");
    XL(14, " offset:896"); XL(15, " offset:960");
}

// ---- persistent LSTM kernel ---------------------------------------------
// 64 WGs x 256 threads, no LDS, no __syncthreads, no flags: each wave
// free-runs, synchronized only by per-dword (tag16|f16) data polling.

__global__ void __launch_bounds__(256, 1) k_lstm(
    const f16* __restrict__ x16, const f16* __restrict__ Wxp,
    const f16* __restrict__ Whp, const float* __restrict__ b,
    u32* hbuf32, float* __restrict__ out)
{
    const int wg  = blockIdx.x;
    const int tid = threadIdx.x;
    const int w   = tid >> 6;
    const int l   = tid & 63;
    const int mt  = w >> 1, nt = w & 1;
    const int lq  = l >> 4, lc = l & 15;

    const int colp = wg * 32 + nt * 16 + lc;   // permuted gate column
    const int gate = lc & 3, j_in = lc >> 2;
    const int hcol = wg * 8 + nt * 4 + j_in;
    const float bv = b[gate * 512 + hcol];

    const int arow   = mt * 16 + lc;           // A-fragment row (batch index)
    const int rm     = l & 3;
    const int n_mine = mt * 16 + lq * 4 + rm;  // row this lane publishes

    // Wh and Wx fragments resident in VGPRs for the entire sequence.
    f16x8 Bh[16], Bx[16];
    {
        const f16* ph = Whp + colp * 512 + lq * 8;
        const f16* px = Wxp + colp * 512 + lq * 8;
        #pragma unroll
        for (int ks = 0; ks < 16; ++ks) {
            Bh[ks] = *(const f16x8*)(ph + ks * 32);
            Bx[ks] = *(const f16x8*)(px + ks * 32);
        }
    }

    const f16* xptr = x16 + arow * (TT * DD) + lq * 8;
    const u32* hb0  = hbuf32 + arow * HH + lq * 8;   // consumer base, buffer 0
    const u32* hb1  = hb0 + NBHH;
    u32* pub0 = hbuf32 + n_mine * HH + hcol;         // producer slot, buffer 0
    u32* pub1 = pub0 + NBHH;
    float* outp = out + (size_t)n_mine * (TT * HH) + hcol;

    float c_reg[4] = {0.f, 0.f, 0.f, 0.f};

    for (int t = 0; t < TT; ++t) {
        const u32* hb = (t & 1) ? hb1 : hb0;
        f16x8 ax[16];
        u32x4 raw[32];
        issue_x(ax, xptr);
        issue_h(raw, hb);
        xptr += DD;

        // ---- poll: all 128 tags of this lane's row must equal t
        int guard = 0;
        for (;;) {
            asm volatile("s_waitcnt vmcnt(0)" ::: "memory");
            __builtin_amdgcn_sched_barrier(0);
            u32 m[16];
            #pragma unroll
            for (int i = 0; i < 16; ++i) {
                u32x4 a = raw[2*i], q = raw[2*i+1];
                u32 x0 = pkmin(pkmin(a[0], a[1]), pkmin(a[2], a[3]));
                u32 x1 = pkmin(pkmin(q[0], q[1]), pkmin(q[2], q[3]));
                m[i] = pkmin(x0, x1);
            }
            #pragma unroll
            for (int s = 8; s >= 1; s >>= 1)
                #pragma unroll
                for (int i = 0; i < s; ++i) m[i] = pkmin(m[i], m[i+s]);
            bool ok = ((m[0] >> 16) == (u32)t);
            if (__all(ok) || ++guard > (1 << 16)) break;
            issue_h(raw, hb);
        }

        // ---- unpack + dual-chain MFMA (x-chain and h-chain independent)
        f32x4 accx = {bv, bv, bv, bv};
        f32x4 acch = {0.f, 0.f, 0.f, 0.f};
        #pragma unroll
        for (int ks = 0; ks < 16; ++ks) {
            u32x4 a = raw[2*ks], q = raw[2*ks+1];
            u32x4 hu;
            hu[0] = __builtin_amdgcn_perm(a[1], a[0], 0x05040100u);
            hu[1] = __builtin_amdgcn_perm(a[3], a[2], 0x05040100u);
            hu[2] = __builtin_amdgcn_perm(q[1], q[0], 0x05040100u);
            hu[3] = __builtin_amdgcn_perm(q[3], q[2], 0x05040100u);
            acch = __builtin_amdgcn_mfma_f32_16x16x32_f16(
                       __builtin_bit_cast(f16x8, hu), Bh[ks], acch, 0, 0, 0);
            accx = __builtin_amdgcn_mfma_f32_16x16x32_f16(ax[ks], Bx[ks], accx, 0, 0, 0);
        }
        f32x4 acc = accx + acch;

        // ---- gates (quad-redundant c state, shuffles within lane-quad)
        float hv = 0.f;
        #pragma unroll
        for (int r = 0; r < 4; ++r) {
            float av = acc[r];
            int base = l & ~3;
            float ai = __shfl(av, base | 0, 64);
            float af = __shfl(av, base | 1, 64);
            float ao = __shfl(av, base | 2, 64);
            float ag = __shfl(av, base | 3, 64);
            float ig = fsig(ai), fg = fsig(af), og = fsig(ao), gg = ftanh(ag);
            float cn = fg * c_reg[r] + ig * gg;
            c_reg[r] = cn;
            float h = og * ftanh(cn);
            if (r == rm) hv = h;
        }

        // ---- publish tagged h_t (tag t+1) first, out-store after (never drained)
        {
            f16 h16 = (f16)hv;
            u32 pub = ((u32)(t + 1) << 16) | (u32)*(unsigned short*)&h16;
            u32* pdst = (t & 1) ? pub0 : pub1;
            asm volatile("global_store_dword %0, %1, off sc0 sc1"
                         :: "v"(pdst), "v"(pub) : "memory");
            outp[(size_t)t * HH] = hv;
        }
    }
}

// ---- launch --------------------------------------------------------------

extern "C" void kernel_launch(void* const* d_in, const int* in_sizes, int n_in,
                              void* d_out, int out_size, void* d_ws, size_t ws_size,
                              hipStream_t stream)
{
    (void)in_sizes; (void)n_in; (void)out_size; (void)ws_size;
    const float* x  = (const float*)d_in[0];
    const float* h0 = (const float*)d_in[1];
    const float* Wx = (const float*)d_in[2];
    const float* Wh = (const float*)d_in[3];
    const float* b  = (const float*)d_in[4];
    float* out = (float*)d_out;

    char* ws = (char*)d_ws;
    f16* x16    = (f16*)ws;                        // 32 MiB
    f16* Wxp    = (f16*)(ws + (32 << 20));         // 2 MiB
    f16* Whp    = (f16*)(ws + (34 << 20));         // 2 MiB
    u32* hbuf32 = (u32*)(ws + (36 << 20));         // 2 x 64 KiB tagged h

    // buffer 1 -> tag 0 (any stale tag from a previous replay is erased;
    // 0 < every expected odd tag, so the min-poll always detects it as stale)
    hipMemsetAsync(hbuf32 + NBHH, 0, NBHH * sizeof(u32), stream);
    k_cast_x<<<8192, 256, 0, stream>>>(x, x16);
    k_perm_w<<<4096, 256, 0, stream>>>(Wx, Wxp);
    k_perm_w<<<4096, 256, 0, stream>>>(Wh, Whp);
    k_h0<<<64, 256, 0, stream>>>(h0, hbuf32);      // buffer 0, tag 0
    k_lstm<<<NWG, 256, 0, stream>>>(x16, Wxp, Whp, b, hbuf32, out);
}

// Round 4
// 7179.366 us; speedup vs baseline: 1.2621x; 1.2621x over previous
//
#include <hip/hip_runtime.h>
#include <cstdint>

typedef _Float16 f16;
typedef f16      f16x8 __attribute__((ext_vector_type(8)));
typedef float    f32x4 __attribute__((ext_vector_type(4)));
typedef uint32_t u32;
typedef u32      u32x4 __attribute__((ext_vector_type(4)));

#define NB    32
#define TT    1024
#define DD    512
#define HH    512
#define NBHH  (NB*HH)
#define NWG   64

__device__ __forceinline__ float fsig(float x) {
    return __builtin_amdgcn_rcpf(1.0f + __expf(-x));
}
__device__ __forceinline__ float ftanh(float x) {
    return 1.0f - 2.0f * __builtin_amdgcn_rcpf(__expf(2.0f * x) + 1.0f);
}

// ---- setup kernels -------------------------------------------------------

__global__ void k_cast_x(const float* __restrict__ x, f16* __restrict__ x16) {
    int i = (blockIdx.x * 256 + threadIdx.x) * 8;
    float4 a = *(const float4*)(x + i);
    float4 c = *(const float4*)(x + i + 4);
    f16x8 v;
    v[0] = (f16)a.x; v[1] = (f16)a.y; v[2] = (f16)a.z; v[3] = (f16)a.w;
    v[4] = (f16)c.x; v[5] = (f16)c.y; v[6] = (f16)c.z; v[7] = (f16)c.w;
    *(f16x8*)(x16 + i) = v;
}

// W (512 x 2048 row-major) -> Wp[colp][k] f16; colp = wg*32 + j*4 + gate,
// col2048 = gate*512 + wg*8 + j.
__global__ void k_perm_w(const float* __restrict__ W, f16* __restrict__ Wp) {
    int tid = blockIdx.x * 256 + threadIdx.x;   // 2048*512
    int colp = tid >> 9, k = tid & 511;
    int wg = colp >> 5, c = colp & 31;
    int gate = c & 3, j = c >> 2;
    int col = gate * 512 + wg * 8 + j;
    Wp[tid] = (f16)W[k * 2048 + col];
}

// h0 -> f16 into buffer 1 (consumed at t=0); dispatch-boundary coherence.
__global__ void k_h0(const float* __restrict__ h0, f16* __restrict__ hb) {
    int i = blockIdx.x * 256 + threadIdx.x;     // 32*512
    hb[i] = (f16)h0[i];
}

// ---- persistent LSTM kernel ---------------------------------------------
// 64 WGs x 256 threads, 1 block/CU. No LDS, no __syncthreads in the loop.
// Per-wave monotone flags (256 u32), dual-parity h buffers, device scope
// (sc0 sc1) for all cross-WG traffic. Every loop is bounded.

__global__ void __launch_bounds__(256, 1) k_lstm(
    const f16* __restrict__ x16, const f16* __restrict__ Wxp,
    const f16* __restrict__ Whp, const float* __restrict__ bb,
    f16* hbuf, u32* flags, float* __restrict__ out)
{
    const int wg  = blockIdx.x;
    const int tid = threadIdx.x;
    const int w   = tid >> 6;
    const int l   = tid & 63;
    const int mt  = w >> 1, nt = w & 1;
    const int lq  = l >> 4, lc = l & 15;

    const int colp = wg * 32 + nt * 16 + lc;   // permuted gate column
    const int gate = lc & 3, j_in = lc >> 2;
    const int hcol = wg * 8 + nt * 4 + j_in;
    const float bv = bb[gate * 512 + hcol];

    const int arow   = mt * 16 + lc;           // A-fragment row (batch index)
    const int rm     = l & 3;                  // == gate
    const int n_mine = mt * 16 + lq * 4 + rm;  // row this lane publishes
    const int widx   = wg * 4 + w;

    // Wh and Wx fragments resident in VGPRs for the whole sequence.
    f16x8 Bh[16], Bx[16];
    {
        const f16* ph = Whp + (size_t)colp * 512 + lq * 8;
        const f16* px = Wxp + (size_t)colp * 512 + lq * 8;
        #pragma unroll
        for (int ks = 0; ks < 16; ++ks) {
            Bh[ks] = *(const f16x8*)(ph + ks * 32);
            Bx[ks] = *(const f16x8*)(px + ks * 32);
        }
    }

    const f16* xptr = x16 + (size_t)arow * (TT * DD) + lq * 8;
    f16* pub0 = hbuf + n_mine * HH + hcol;     // parity-0 publish slot
    f16* pub1 = pub0 + NBHH;
    float* outp = out + (size_t)n_mine * (TT * HH) + hcol;
    const u32* fl = flags + l * 4;             // 64 lanes x 4 = all 256 flags
    u32* myflag = flags + widx;

    float c_reg[4] = {0.f, 0.f, 0.f, 0.f};

    for (int t = 0; t < TT; ++t) {
        // ---- x_t @ Wx + b : independent of h, overlaps others' tails
        f32x4 acc = {bv, bv, bv, bv};
        {
            const f16* xp = xptr + (size_t)t * DD;
            #pragma unroll
            for (int ks = 0; ks < 16; ++ks) {
                f16x8 ax = *(const f16x8*)(xp + ks * 32);
                acc = __builtin_amdgcn_mfma_f32_16x16x32_f16(ax, Bx[ks], acc, 0, 0, 0);
            }
        }
        // ---- poll all 256 per-wave flags (retry = one dwordx4 per lane)
        if (t) {
            int guard = 0;
            for (;;) {
                u32x4 f;
                asm volatile("global_load_dwordx4 %0, %1, off sc0 sc1"
                             : "=v"(f) : "v"(fl));
                asm volatile("s_waitcnt vmcnt(0)" ::: "memory");
                u32 m0 = f[0] < f[1] ? f[0] : f[1];
                u32 m1 = f[2] < f[3] ? f[2] : f[3];
                u32 m  = m0 < m1 ? m0 : m1;
                if (__all(m >= (u32)t) || ++guard > (1 << 20)) break;
            }
        }
        __builtin_amdgcn_sched_barrier(0);
        // ---- h_{t-1} @ Wh (device-scope loads, bypass stale L1/L2)
        {
            u32x4 hw[16];
            const f16* hb = hbuf + ((t & 1) ? 0 : NBHH) + arow * HH + lq * 8;
#define HLD(I, OFF) asm volatile("global_load_dwordx4 %0, %1, off" OFF " sc0 sc1" \
                                 : "=v"(hw[I]) : "v"(hb))
            HLD(0, "");             HLD(1,  " offset:64");
            HLD(2,  " offset:128"); HLD(3,  " offset:192");
            HLD(4,  " offset:256"); HLD(5,  " offset:320");
            HLD(6,  " offset:384"); HLD(7,  " offset:448");
            HLD(8,  " offset:512"); HLD(9,  " offset:576");
            HLD(10, " offset:640"); HLD(11, " offset:704");
            HLD(12, " offset:768"); HLD(13, " offset:832");
            HLD(14, " offset:896"); HLD(15, " offset:960");
#undef HLD
            asm volatile("s_waitcnt vmcnt(0)" ::: "memory");
            __builtin_amdgcn_sched_barrier(0);
            #pragma unroll
            for (int ks = 0; ks < 16; ++ks)
                acc = __builtin_amdgcn_mfma_f32_16x16x32_f16(
                          __builtin_bit_cast(f16x8, hw[ks]), Bh[ks], acc, 0, 0, 0);
        }
        // ---- gates (quad-redundant c state, intra-quad shuffles)
        float hv = 0.f;
        #pragma unroll
        for (int r = 0; r < 4; ++r) {
            float av = acc[r];
            int base = l & ~3;
            float ai = __shfl(av, base | 0, 64);
            float af = __shfl(av, base | 1, 64);
            float ao = __shfl(av, base | 2, 64);
            float ag = __shfl(av, base | 3, 64);
            float ig = fsig(ai), fg = fsig(af), og = fsig(ao), gg = ftanh(ag);
            float cn = fg * c_reg[r] + ig * gg;
            c_reg[r] = cn;
            float h = og * ftanh(cn);
            if (r == rm) hv = h;
        }
        // ---- publish h_t -> drain -> flag; out-store last (its ack is
        // absorbed by next step's drain, fully covered by x-MFMA+poll+h-load)
        f16 h16 = (f16)hv;
        u32 hvu = (u32)__builtin_bit_cast(unsigned short, h16);
        {
            f16* pdst = (t & 1) ? pub1 : pub0;
            asm volatile("global_store_short %0, %1, off sc0 sc1"
                         :: "v"(pdst), "v"(hvu) : "memory");
        }
        asm volatile("s_waitcnt vmcnt(0)" ::: "memory");
        if (l == 0) {
            u32 fv = (u32)(t + 1);
            asm volatile("global_store_dword %0, %1, off sc0 sc1"
                         :: "v"(myflag), "v"(fv) : "memory");
        }
        outp[(size_t)t * HH] = hv;
    }
}

// ---- launch --------------------------------------------------------------

extern "C" void kernel_launch(void* const* d_in, const int* in_sizes, int n_in,
                              void* d_out, int out_size, void* d_ws, size_t ws_size,
                              hipStream_t stream)
{
    (void)in_sizes; (void)n_in; (void)out_size; (void)ws_size;
    const float* x  = (const float*)d_in[0];
    const float* h0 = (const float*)d_in[1];
    const float* Wx = (const float*)d_in[2];
    const float* Wh = (const float*)d_in[3];
    const float* b  = (const float*)d_in[4];
    float* out = (float*)d_out;

    char* ws = (char*)d_ws;
    u32* flags = (u32*)ws;                               // 4 KiB reserved
    f16* x16   = (f16*)(ws + (4 << 10));                 // 32 MiB
    f16* Wxp   = (f16*)(ws + (4 << 10) + (32 << 20));    // 2 MiB
    f16* Whp   = (f16*)(ws + (4 << 10) + (34 << 20));    // 2 MiB
    f16* hbuf  = (f16*)(ws + (4 << 10) + (36 << 20));    // 2 x 64 KiB

    hipMemsetAsync(flags, 0, 4096, stream);
    k_cast_x<<<8192, 256, 0, stream>>>(x, x16);
    k_perm_w<<<4096, 256, 0, stream>>>(Wx, Wxp);
    k_perm_w<<<4096, 256, 0, stream>>>(Wh, Whp);
    k_h0<<<64, 256, 0, stream>>>(h0, hbuf + NBHH);       // buffer 1 = h_{-1}
    k_lstm<<<NWG, 256, 0, stream>>>(x16, Wxp, Whp, b, hbuf, flags, out);
}

// Round 5
// 4534.463 us; speedup vs baseline: 1.9982x; 1.5833x over previous
//
#include <hip/hip_runtime.h>
#include <cstdint>

typedef _Float16 f16;
typedef f16      f16x8 __attribute__((ext_vector_type(8)));
typedef float    f32x4 __attribute__((ext_vector_type(4)));
typedef uint32_t u32;
typedef u32      u32x4 __attribute__((ext_vector_type(4)));

#define NB    32
#define TT    1024
#define DD    512
#define HH    512
#define NBHH  (NB*HH)
#define NWG   64

__device__ __forceinline__ float fsig(float x) {
    return __builtin_amdgcn_rcpf(1.0f + __expf(-x));
}
__device__ __forceinline__ float ftanh(float x) {
    return 1.0f - 2.0f * __builtin_amdgcn_rcpf(__expf(2.0f * x) + 1.0f);
}

// ---- setup kernels -------------------------------------------------------

__global__ void k_cast_x(const float* __restrict__ x, f16* __restrict__ x16) {
    int i = (blockIdx.x * 256 + threadIdx.x) * 8;
    float4 a = *(const float4*)(x + i);
    float4 c = *(const float4*)(x + i + 4);
    f16x8 v;
    v[0] = (f16)a.x; v[1] = (f16)a.y; v[2] = (f16)a.z; v[3] = (f16)a.w;
    v[4] = (f16)c.x; v[5] = (f16)c.y; v[6] = (f16)c.z; v[7] = (f16)c.w;
    *(f16x8*)(x16 + i) = v;
}

// W (512 x 2048 row-major) -> Wp[colp][k] f16; colp = wg*32 + j*4 + gate,
// col2048 = gate*512 + wg*8 + j.
__global__ void k_perm_w(const float* __restrict__ W, f16* __restrict__ Wp) {
    int tid = blockIdx.x * 256 + threadIdx.x;   // 2048*512
    int colp = tid >> 9, k = tid & 511;
    int wg = colp >> 5, c = colp & 31;
    int gate = c & 3, j = c >> 2;
    int col = gate * 512 + wg * 8 + j;
    Wp[tid] = (f16)W[k * 2048 + col];
}

// h0 -> f16 into buffer 1 (consumed at t=0); dispatch-boundary coherence.
__global__ void k_h0(const float* __restrict__ h0, f16* __restrict__ hb) {
    int i = blockIdx.x * 256 + threadIdx.x;     // 32*512
    hb[i] = (f16)h0[i];
}

// ---- persistent LSTM kernel ---------------------------------------------
// 64 WGs x 256 threads. Monotone per-WG flags (64), dual-parity h buffers,
// device scope (sc0 sc1) for all cross-WG traffic. All cross-WG streams
// coalesced: h staged through LDS (full-line loads), h published as 32x16B,
// out buffered in LDS and flushed every 32 steps as cached float4.

__global__ void __launch_bounds__(256, 1) k_lstm(
    const f16* __restrict__ x16, const f16* __restrict__ Wxp,
    const f16* __restrict__ Whp, const float* __restrict__ bb,
    f16* hbuf, u32* flags, float* __restrict__ out)
{
    __shared__ unsigned char lds_h[32768];   // staged h_{t-1} (swizzled)
    __shared__ u32           lds_pub[256];   // this WG's h_t slice (32n x 8c)
    __shared__ float         lds_out[8192];  // 32 steps x 256 out values

    const int wg  = blockIdx.x;
    const int tid = threadIdx.x;
    const int w   = tid >> 6;
    const int l   = tid & 63;
    const int mt  = w >> 1, nt = w & 1;
    const int lq  = l >> 4, lc = l & 15;

    const int colp = wg * 32 + nt * 16 + lc;   // permuted gate column
    const int gate = lc & 3, j_in = lc >> 2;
    const int hcol = wg * 8 + nt * 4 + j_in;
    const int hc8  = nt * 4 + j_in;            // 0..7 within WG slice
    const float bv = bb[gate * 512 + hcol];

    const int arow   = mt * 16 + lc;           // A-fragment row (batch index)
    const int rm     = l & 3;                  // == gate
    const int n_mine = mt * 16 + lq * 4 + rm;  // row this lane produces

    // Wh and Wx fragments resident in VGPRs for the whole sequence.
    f16x8 Bh[16], Bx[16];
    {
        const f16* ph = Whp + (size_t)colp * 512 + lq * 8;
        const f16* px = Wxp + (size_t)colp * 512 + lq * 8;
        #pragma unroll
        for (int ks = 0; ks < 16; ++ks) {
            Bh[ks] = *(const f16x8*)(ph + ks * 32);
            Bx[ks] = *(const f16x8*)(px + ks * 32);
        }
    }

    const f16* xptr = x16 + (size_t)arow * (TT * DD) + lq * 8;

    float c_reg[4] = {0.f, 0.f, 0.f, 0.f};

    for (int t = 0; t < TT; ++t) {
        // ---- x_t @ Wx + b : independent of h, overlaps others' tails
        f32x4 acc = {bv, bv, bv, bv};
        {
            const f16* xp = xptr + (size_t)t * DD;
            #pragma unroll
            for (int ks = 0; ks < 16; ++ks) {
                f16x8 ax = *(const f16x8*)(xp + ks * 32);
                acc = __builtin_amdgcn_mfma_f32_16x16x32_f16(ax, Bx[ks], acc, 0, 0, 0);
            }
        }
        // ---- poll 64 per-WG flags (retry = one dword per lane, 4 lines)
        if (t) {
            const u32* fl = flags + l;
            int guard = 0;
            for (;;) {
                u32 f;
                asm volatile("global_load_dword %0, %1, off sc0 sc1"
                             : "=v"(f) : "v"(fl));
                asm volatile("s_waitcnt vmcnt(0)" ::: "memory");
                if (__all(f >= (u32)t) || ++guard > (1 << 20)) break;
            }
        }
        __builtin_amdgcn_sched_barrier(0);
        // ---- cooperative stage: full 32KB h_{t-1} -> LDS, wave-contiguous
        {
            const char* gp = (const char*)(hbuf + ((t & 1) ? 0 : NBHH)) + tid * 16;
            u32x4 hv4[8];
            #pragma unroll
            for (int r = 0; r < 8; ++r) {
                const char* p = gp + r * 4096;
                asm volatile("global_load_dwordx4 %0, %1, off sc0 sc1"
                             : "=v"(hv4[r]) : "v"(p));
            }
            asm volatile("s_waitcnt vmcnt(0)" ::: "memory");
            __builtin_amdgcn_sched_barrier(0);
            const int inrow = (tid & 63) * 16;
            #pragma unroll
            for (int r = 0; r < 8; ++r) {
                int row = (tid >> 6) + 4 * r;
                int off = row * 1024 + (inrow ^ ((row & 7) << 4));
                *(u32x4*)&lds_h[off] = hv4[r];
            }
        }
        __syncthreads();
        // ---- h_{t-1} @ Wh from LDS (2-way banked via XOR swizzle)
        {
            const int swz   = (arow & 7) << 4;
            const int baseA = arow * 1024;
            #pragma unroll
            for (int ks = 0; ks < 16; ++ks) {
                int inrowA = lq * 16 + ks * 64;
                u32x4 a = *(const u32x4*)&lds_h[baseA + (inrowA ^ swz)];
                acc = __builtin_amdgcn_mfma_f32_16x16x32_f16(
                          __builtin_bit_cast(f16x8, a), Bh[ks], acc, 0, 0, 0);
            }
        }
        // ---- gates (quad-redundant c state, intra-quad shuffles)
        float hv = 0.f;
        #pragma unroll
        for (int r = 0; r < 4; ++r) {
            float av = acc[r];
            int base = l & ~3;
            float ai = __shfl(av, base | 0, 64);
            float af = __shfl(av, base | 1, 64);
            float ao = __shfl(av, base | 2, 64);
            float ag = __shfl(av, base | 3, 64);
            float ig = fsig(ai), fg = fsig(af), og = fsig(ao), gg = ftanh(ag);
            float cn = fg * c_reg[r] + ig * gg;
            c_reg[r] = cn;
            float h = og * ftanh(cn);
            if (r == rm) hv = h;
        }
        // ---- stage h_t slice + out value in LDS
        {
            f16 h16 = (f16)hv;
            lds_pub[n_mine * 8 + hc8] = (u32)__builtin_bit_cast(unsigned short, h16);
            lds_out[(t & 31) * 256 + n_mine * 8 + hc8] = hv;
        }
        __syncthreads();
        // ---- wave0: publish WG slice as 32 x 16B contiguous, drain, flag
        if (w == 0) {
            if (tid < 32) {
                const u32* pp = lds_pub + tid * 8;
                u32 p0 = (pp[0] & 0xffffu) | (pp[1] << 16);
                u32 p1 = (pp[2] & 0xffffu) | (pp[3] << 16);
                u32 p2 = (pp[4] & 0xffffu) | (pp[5] << 16);
                u32 p3 = (pp[6] & 0xffffu) | (pp[7] << 16);
                u32x4 pv = {p0, p1, p2, p3};
                f16* hdst = hbuf + ((t & 1) ? NBHH : 0) + tid * HH + wg * 8;
                asm volatile("global_store_dwordx4 %0, %1, off sc0 sc1"
                             :: "v"(hdst), "v"(pv) : "memory");
            }
            asm volatile("s_waitcnt vmcnt(0)" ::: "memory");
            if (tid == 0) {
                u32 fv = (u32)(t + 1);
                u32* mf = flags + wg;
                asm volatile("global_store_dword %0, %1, off sc0 sc1"
                             :: "v"(mf), "v"(fv) : "memory");
            }
        }
        // ---- flush 32 steps of out as plain cached float4 (off hot path)
        if ((t & 31) == 31) {
            #pragma unroll
            for (int r2 = 0; r2 < 8; ++r2) {
                int tau = tid + 256 * r2;         // (s*32 + n)*2 + hc4
                int s   = tau >> 6;
                int n2  = (tau >> 1) & 31;
                int hc4 = tau & 1;
                float4 v = *(const float4*)&lds_out[s * 256 + n2 * 8 + hc4 * 4];
                float* op = out + (size_t)n2 * (TT * HH)
                                + (size_t)(t - 31 + s) * HH + wg * 8 + hc4 * 4;
                *(float4*)op = v;
            }
        }
    }
}

// ---- launch --------------------------------------------------------------

extern "C" void kernel_launch(void* const* d_in, const int* in_sizes, int n_in,
                              void* d_out, int out_size, void* d_ws, size_t ws_size,
                              hipStream_t stream)
{
    (void)in_sizes; (void)n_in; (void)out_size; (void)ws_size;
    const float* x  = (const float*)d_in[0];
    const float* h0 = (const float*)d_in[1];
    const float* Wx = (const float*)d_in[2];
    const float* Wh = (const float*)d_in[3];
    const float* b  = (const float*)d_in[4];
    float* out = (float*)d_out;

    char* ws = (char*)d_ws;
    u32* flags = (u32*)ws;                               // 4 KiB reserved
    f16* x16   = (f16*)(ws + (4 << 10));                 // 32 MiB
    f16* Wxp   = (f16*)(ws + (4 << 10) + (32 << 20));    // 2 MiB
    f16* Whp   = (f16*)(ws + (4 << 10) + (34 << 20));    // 2 MiB
    f16* hbuf  = (f16*)(ws + (4 << 10) + (36 << 20));    // 2 x 64 KiB

    hipMemsetAsync(flags, 0, 4096, stream);
    k_cast_x<<<8192, 256, 0, stream>>>(x, x16);
    k_perm_w<<<4096, 256, 0, stream>>>(Wx, Wxp);
    k_perm_w<<<4096, 256, 0, stream>>>(Wh, Whp);
    k_h0<<<64, 256, 0, stream>>>(h0, hbuf + NBHH);       // buffer 1 = h_{-1}
    k_lstm<<<NWG, 256, 0, stream>>>(x16, Wxp, Whp, b, hbuf, flags, out);
}